// Round 1
// baseline (499.676 us; speedup 1.0000x reference)
//
#include <hip/hip_runtime.h>
#include <hip/hip_bf16.h>

#define B_ 32
#define T_ 4096
#define F_ 512
#define H_ 512

typedef float floatx4 __attribute__((ext_vector_type(4)));
typedef short short8 __attribute__((ext_vector_type(8)));

__device__ __forceinline__ unsigned pack2_bf16(float a, float b) {
  unsigned ua = __float_as_uint(a);
  unsigned ub = __float_as_uint(b);
  ua = (ua + 0x7FFFu + ((ua >> 16) & 1u)) >> 16;           // RNE -> low half
  ub = (ub + 0x7FFFu + ((ub >> 16) & 1u)) & 0xFFFF0000u;   // RNE -> high half
  return ua | ub;
}

__device__ __forceinline__ unsigned short f2bf16(float a) {
  unsigned ua = __float_as_uint(a);
  return (unsigned short)((ua + 0x7FFFu + ((ua >> 16) & 1u)) >> 16);
}

// tanh(x) = 1 - 2/(e^{2x}+1); graceful at +/-inf, ~1e-7 abs err near 0.
__device__ __forceinline__ float tanh_fast(float x) {
  float e = __expf(2.0f * x);
  return 1.0f - __fdividef(2.0f, e + 1.0f);
}

__device__ __forceinline__ void async_load16(const void* g, void* l) {
  __builtin_amdgcn_global_load_lds(
      (const __attribute__((address_space(1))) void*)g,
      (__attribute__((address_space(3))) void*)l, 16, 0, 0);
}

// ---- prep: W1 [F][H] fp32 -> W1T [H][F] bf16 (B-operand layout) ----
__global__ void prep_w1t(const float* __restrict__ W1, unsigned short* __restrict__ W1T) {
  __shared__ float tile[32][33];
  const int tx = threadIdx.x, ty = threadIdx.y;
  const int f = blockIdx.y * 32 + ty;
  const int h = blockIdx.x * 32 + tx;
  tile[ty][tx] = W1[f * H_ + h];
  __syncthreads();
  const int ho = blockIdx.x * 32 + ty;
  const int fo = blockIdx.y * 32 + tx;
  W1T[ho * F_ + fo] = f2bf16(tile[tx][ty]);
}

// ---- prep: w2d[b][h] = dec[b][:] . W2[:][h], fp32 ----
__global__ void prep_w2d(const float* __restrict__ dec, const float* __restrict__ W2,
                         float* __restrict__ w2d) {
  const int b = blockIdx.x, h = threadIdx.x;
  float s0 = 0.f, s1 = 0.f, s2 = 0.f, s3 = 0.f;
  for (int f = 0; f < F_; f += 4) {
    s0 += dec[b * F_ + f + 0] * W2[(f + 0) * H_ + h];
    s1 += dec[b * F_ + f + 1] * W2[(f + 1) * H_ + h];
    s2 += dec[b * F_ + f + 2] * W2[(f + 2) * H_ + h];
    s3 += dec[b * F_ + f + 3] * W2[(f + 3) * H_ + h];
  }
  w2d[b * H_ + h] = (s0 + s1) + (s2 + s3);
}

// ---- main: fused (enc@W1) -> tanh(+w2d) -> .V row-reduce -> atomic scores ----
// grid = 4096: bid>>2 = m-tile (128 rows of B*T), bid&3 = n-tile (128 of H=512)
__global__ __launch_bounds__(256) void fused_score(
    const float* __restrict__ enc, const unsigned short* __restrict__ W1T,
    const float* __restrict__ w2d, const float* __restrict__ V,
    float* __restrict__ scores) {
  __shared__ __align__(16) unsigned short As[128 * 32];  // [m][k] 64B rows
  __shared__ __align__(16) unsigned short Bs[128 * 32];  // [n][k] 64B rows

  const int tid = threadIdx.x;
  const int bid = blockIdx.x;
  const int m_blk = bid >> 2;
  const int n_blk = bid & 3;
  const int lane = tid & 63;
  const int wave = tid >> 6;
  const int wm = wave >> 1;
  const int wn = wave & 1;
  const int quad = lane >> 4;
  const int l16 = lane & 15;

  // A staging: each thread loads one float4 per 32-row group, 4 groups
  const int arow = tid >> 3;       // 0..31
  const int acol = (tid & 7) * 4;  // float offset within 32-wide k-chunk
  const float* aptr = enc + (size_t)(m_blk * 128 + arow) * F_ + acol;

  // B staging via global_load_lds: wave covers n-rows [nb0, nb0+32) in two 1KB ops
  const int nb0 = wave * 32;
  const unsigned short* bsrc0 =
      W1T + (size_t)(n_blk * 128 + nb0 + (lane >> 2)) * F_ + (lane & 3) * 8;
  const unsigned short* bsrc1 = bsrc0 + 16 * F_;
  unsigned short* bdst0 = &Bs[nb0 * 32];
  unsigned short* bdst1 = &Bs[(nb0 + 16) * 32];

  floatx4 acc[4][4];
#pragma unroll
  for (int i = 0; i < 4; i++)
#pragma unroll
    for (int j = 0; j < 4; j++) acc[i][j] = (floatx4){0.f, 0.f, 0.f, 0.f};

  for (int ks = 0; ks < 16; ++ks) {
    const int k0 = ks * 32;
    __syncthreads();  // prior iter's LDS reads done before overwrite
    async_load16(bsrc0 + k0, bdst0);
    async_load16(bsrc1 + k0, bdst1);
#pragma unroll
    for (int rr = 0; rr < 4; ++rr) {
      const float4 v = *(const float4*)(aptr + rr * 32 * F_ + k0);
      uint2 pk;
      pk.x = pack2_bf16(v.x, v.y);
      pk.y = pack2_bf16(v.z, v.w);
      *(uint2*)&As[(arow + rr * 32) * 32 + acol] = pk;
    }
    __syncthreads();  // drains vmcnt(0): global_load_lds + ds_writes visible

    short8 af[4], bfr[4];
#pragma unroll
    for (int i = 0; i < 4; i++)
      af[i] = *(const short8*)&As[(wm * 64 + i * 16 + l16) * 32 + quad * 8];
#pragma unroll
    for (int j = 0; j < 4; j++)
      bfr[j] = *(const short8*)&Bs[(wn * 64 + j * 16 + l16) * 32 + quad * 8];
#pragma unroll
    for (int i = 0; i < 4; i++)
#pragma unroll
      for (int j = 0; j < 4; j++)
        acc[i][j] = __builtin_amdgcn_mfma_f32_16x16x32_bf16(af[i], bfr[j], acc[i][j], 0, 0, 0);
  }

  // epilogue: C/D layout col=lane&15, row=quad*4+reg (m89/m91-verified)
  const int b = m_blk >> 5;  // 32 m-tiles per batch row (T/128)
  float w2v[4], vv[4];
#pragma unroll
  for (int j = 0; j < 4; j++) {
    const int h = n_blk * 128 + wn * 64 + j * 16 + l16;
    w2v[j] = w2d[b * H_ + h];
    vv[j] = V[h];
  }
  float rs[4][4];
#pragma unroll
  for (int i = 0; i < 4; i++)
#pragma unroll
    for (int r = 0; r < 4; r++) {
      float s = 0.f;
#pragma unroll
      for (int j = 0; j < 4; j++) s += tanh_fast(acc[i][j][r] + w2v[j]) * vv[j];
      rs[i][r] = s;
    }
  // reduce across the 16 column-lanes of each quad
#pragma unroll
  for (int i = 0; i < 4; i++)
#pragma unroll
    for (int r = 0; r < 4; r++) {
      float s = rs[i][r];
      s += __shfl_xor(s, 1, 16);
      s += __shfl_xor(s, 2, 16);
      s += __shfl_xor(s, 4, 16);
      s += __shfl_xor(s, 8, 16);
      rs[i][r] = s;
    }
  if (l16 == 0) {
#pragma unroll
    for (int i = 0; i < 4; i++)
#pragma unroll
      for (int r = 0; r < 4; r++)
        atomicAdd(&scores[m_blk * 128 + wm * 64 + i * 16 + quad * 4 + r], rs[i][r]);
  }
}

// ---- softmax over T per batch row ----
__global__ __launch_bounds__(256) void softmax_rows(const float* __restrict__ scores,
                                                    float* __restrict__ out) {
  const int b = blockIdx.x;
  const int tid = threadIdx.x;
  const int wave = tid >> 6;
  __shared__ float red[4];
  float v[16];
  float mx = -1e30f;
#pragma unroll
  for (int i = 0; i < 16; i++) {
    v[i] = scores[b * T_ + i * 256 + tid];
    mx = fmaxf(mx, v[i]);
  }
#pragma unroll
  for (int o = 32; o > 0; o >>= 1) mx = fmaxf(mx, __shfl_xor(mx, o, 64));
  if ((tid & 63) == 0) red[wave] = mx;
  __syncthreads();
  mx = fmaxf(fmaxf(red[0], red[1]), fmaxf(red[2], red[3]));
  __syncthreads();
  float sum = 0.f;
#pragma unroll
  for (int i = 0; i < 16; i++) {
    v[i] = __expf(v[i] - mx);
    sum += v[i];
  }
#pragma unroll
  for (int o = 32; o > 0; o >>= 1) sum += __shfl_xor(sum, o, 64);
  if ((tid & 63) == 0) red[wave] = sum;
  __syncthreads();
  sum = (red[0] + red[1]) + (red[2] + red[3]);
  const float inv = 1.0f / sum;
#pragma unroll
  for (int i = 0; i < 16; i++) out[b * T_ + i * 256 + tid] = v[i] * inv;
}

extern "C" void kernel_launch(void* const* d_in, const int* in_sizes, int n_in,
                              void* d_out, int out_size, void* d_ws, size_t ws_size,
                              hipStream_t stream) {
  const float* enc = (const float*)d_in[0];  // [B,T,F]
  const float* dec = (const float*)d_in[1];  // [B,F]
  const float* W1 = (const float*)d_in[2];   // [F,H]
  const float* W2 = (const float*)d_in[3];   // [F,H]
  const float* V = (const float*)d_in[4];    // [H,1]
  float* out = (float*)d_out;                // [B,T]

  char* ws = (char*)d_ws;
  float* scores = (float*)ws;                            // 512 KB
  unsigned short* W1T = (unsigned short*)(ws + 524288);  // 512 KB
  float* w2d = (float*)(ws + 1048576);                   // 64 KB

  (void)in_sizes; (void)n_in; (void)out_size; (void)ws_size;

  hipMemsetAsync(scores, 0, B_ * T_ * sizeof(float), stream);
  prep_w1t<<<dim3(16, 16), dim3(32, 32), 0, stream>>>(W1, W1T);
  prep_w2d<<<dim3(32), dim3(512), 0, stream>>>(dec, W2, w2d);
  fused_score<<<dim3(4096), dim3(256), 0, stream>>>(enc, W1T, w2d, V, scores);
  softmax_rows<<<dim3(32), dim3(256), 0, stream>>>(scores, out);
}

// Round 2
// 477.868 us; speedup vs baseline: 1.0456x; 1.0456x over previous
//
#include <hip/hip_runtime.h>
#include <hip/hip_bf16.h>

#define B_ 32
#define T_ 4096
#define F_ 512
#define H_ 512

typedef float floatx4 __attribute__((ext_vector_type(4)));
typedef short short8 __attribute__((ext_vector_type(8)));

__device__ __forceinline__ unsigned pack2_bf16(float a, float b) {
  unsigned ua = __float_as_uint(a);
  unsigned ub = __float_as_uint(b);
  ua = (ua + 0x7FFFu + ((ua >> 16) & 1u)) >> 16;           // RNE -> low half
  ub = (ub + 0x7FFFu + ((ub >> 16) & 1u)) & 0xFFFF0000u;   // RNE -> high half
  return ua | ub;
}

__device__ __forceinline__ unsigned short f2bf16(float a) {
  unsigned ua = __float_as_uint(a);
  return (unsigned short)((ua + 0x7FFFu + ((ua >> 16) & 1u)) >> 16);
}

// tanh(x) = 1 - 2/(e^{2x}+1); graceful at +/-inf.
__device__ __forceinline__ float tanh_fast(float x) {
  float e = __expf(2.0f * x);
  return 1.0f - __fdividef(2.0f, e + 1.0f);
}

__device__ __forceinline__ void async_load16(const void* g, void* l) {
  __builtin_amdgcn_global_load_lds(
      (const __attribute__((address_space(1))) void*)g,
      (__attribute__((address_space(3))) void*)l, 16, 0, 0);
}

// ---- prep: W1 [F][H] fp32 -> W1T [H][F] bf16 (B-operand layout) ----
__global__ void prep_w1t(const float* __restrict__ W1, unsigned short* __restrict__ W1T) {
  __shared__ float tile[32][33];
  const int tx = threadIdx.x, ty = threadIdx.y;
  const int f = blockIdx.y * 32 + ty;
  const int h = blockIdx.x * 32 + tx;
  tile[ty][tx] = W1[f * H_ + h];
  __syncthreads();
  const int ho = blockIdx.x * 32 + ty;
  const int fo = blockIdx.y * 32 + tx;
  W1T[ho * F_ + fo] = f2bf16(tile[tx][ty]);
}

// ---- prep: w2d[b][h] = dec[b][:] . W2[:][h], fp32. 128 blocks x 128 thr ----
__global__ __launch_bounds__(128) void prep_w2d(const float* __restrict__ dec,
                                                const float* __restrict__ W2,
                                                float* __restrict__ w2d) {
  const int b = blockIdx.x;
  const int h = blockIdx.y * 128 + threadIdx.x;
  float s0 = 0.f, s1 = 0.f, s2 = 0.f, s3 = 0.f;
  for (int f = 0; f < F_; f += 4) {
    s0 += dec[b * F_ + f + 0] * W2[(f + 0) * H_ + h];
    s1 += dec[b * F_ + f + 1] * W2[(f + 1) * H_ + h];
    s2 += dec[b * F_ + f + 2] * W2[(f + 2) * H_ + h];
    s3 += dec[b * F_ + f + 3] * W2[(f + 3) * H_ + h];
  }
  w2d[b * H_ + h] = (s0 + s1) + (s2 + s3);
}

// ---- main: fused (enc@W1) -> tanh(+w2d) -> .V row-reduce -> atomic scores ----
// XCD-swizzled grid: xcd = bid&7; i = bid>>3; n_blk = i&3; m_blk = xcd + 8*(i>>2)
// -> the 4 n-blocks of one m-tile all land on the same XCD, consecutively.
__global__ __launch_bounds__(256, 3) void fused_score(
    const float* __restrict__ enc, const unsigned short* __restrict__ W1T,
    const float* __restrict__ w2d, const float* __restrict__ V,
    float* __restrict__ scores) {
  // As padded to 40 shorts/row (80B): 8-way -> 2-way bank conflicts (free).
  // Bs must stay lane-linear for global_load_lds -> XOR k-chunk swizzle instead.
  __shared__ __align__(16) unsigned short As[2][128 * 40];
  __shared__ __align__(16) unsigned short Bs[2][128 * 32];

  const int tid = threadIdx.x;
  const int bid = blockIdx.x;
  const int xcd = bid & 7;
  const int ii = bid >> 3;
  const int n_blk = ii & 3;
  const int m_blk = xcd + ((ii >> 2) << 3);
  const int lane = tid & 63;
  const int wave = tid >> 6;
  const int wm = wave >> 1;
  const int wn = wave & 1;
  const int quad = lane >> 4;
  const int l16 = lane & 15;

  // A staging: thread covers 8 consecutive floats in rows {arow, arow+64}
  const int arow = tid >> 2;       // 0..63
  const int acol = (tid & 3) * 8;  // float offset within 32-wide k-chunk
  const float* aptr = enc + (size_t)(m_blk * 128 + arow) * F_ + acol;

  // B staging via global_load_lds: dst is wave-uniform base + lane*16B.
  // Source XOR-swizzled so LDS slot (n, c) holds k-chunk c ^ (n&3).
  const int nb0 = wave * 32;
  const int bl_n = lane >> 2;
  const int bl_c = (lane & 3) ^ (bl_n & 3);
  const unsigned short* bsrc0 =
      W1T + (size_t)(n_blk * 128 + nb0 + bl_n) * F_ + bl_c * 8;
  const unsigned short* bsrc1 = bsrc0 + 16 * F_;

  floatx4 acc[4][4];
#pragma unroll
  for (int i = 0; i < 4; i++)
#pragma unroll
    for (int j = 0; j < 4; j++) acc[i][j] = (floatx4){0.f, 0.f, 0.f, 0.f};

  float4 a_pre[4];

  // ---- prologue: stage k-chunk 0 into buffer 0 ----
#pragma unroll
  for (int rr = 0; rr < 2; ++rr) {
    a_pre[rr * 2 + 0] = *(const float4*)(aptr + rr * 64 * F_ + 0);
    a_pre[rr * 2 + 1] = *(const float4*)(aptr + rr * 64 * F_ + 4);
  }
#pragma unroll
  for (int rr = 0; rr < 2; ++rr) {
    uint4 pk;
    pk.x = pack2_bf16(a_pre[rr * 2].x, a_pre[rr * 2].y);
    pk.y = pack2_bf16(a_pre[rr * 2].z, a_pre[rr * 2].w);
    pk.z = pack2_bf16(a_pre[rr * 2 + 1].x, a_pre[rr * 2 + 1].y);
    pk.w = pack2_bf16(a_pre[rr * 2 + 1].z, a_pre[rr * 2 + 1].w);
    *(uint4*)&As[0][(arow + rr * 64) * 40 + acol] = pk;
  }
  async_load16(bsrc0, &Bs[0][nb0 * 32]);
  async_load16(bsrc1, &Bs[0][(nb0 + 16) * 32]);
  __syncthreads();

  // ---- main K loop: single barrier per step, double-buffered ----
  for (int ks = 0; ks < 16; ++ks) {
    const int cur = ks & 1;
    const int nxt = cur ^ 1;

    if (ks < 15) {
      const int k1 = (ks + 1) * 32;
      // issue next-step VMEM early: in flight across the whole MFMA block
#pragma unroll
      for (int rr = 0; rr < 2; ++rr) {
        a_pre[rr * 2 + 0] = *(const float4*)(aptr + rr * 64 * F_ + k1);
        a_pre[rr * 2 + 1] = *(const float4*)(aptr + rr * 64 * F_ + k1 + 4);
      }
      async_load16(bsrc0 + k1, &Bs[nxt][nb0 * 32]);
      async_load16(bsrc1 + k1, &Bs[nxt][(nb0 + 16) * 32]);
    }

    short8 af[4], bfr[4];
#pragma unroll
    for (int i = 0; i < 4; i++)
      af[i] = *(const short8*)&As[cur][(wm * 64 + i * 16 + l16) * 40 + quad * 8];
#pragma unroll
    for (int j = 0; j < 4; j++)
      bfr[j] = *(const short8*)&Bs[cur][(wn * 64 + j * 16 + l16) * 32 +
                                        ((quad ^ (l16 & 3)) * 8)];
#pragma unroll
    for (int i = 0; i < 4; i++)
#pragma unroll
      for (int j = 0; j < 4; j++)
        acc[i][j] = __builtin_amdgcn_mfma_f32_16x16x32_bf16(af[i], bfr[j], acc[i][j], 0, 0, 0);

    if (ks < 15) {
#pragma unroll
      for (int rr = 0; rr < 2; ++rr) {
        uint4 pk;
        pk.x = pack2_bf16(a_pre[rr * 2].x, a_pre[rr * 2].y);
        pk.y = pack2_bf16(a_pre[rr * 2].z, a_pre[rr * 2].w);
        pk.z = pack2_bf16(a_pre[rr * 2 + 1].x, a_pre[rr * 2 + 1].y);
        pk.w = pack2_bf16(a_pre[rr * 2 + 1].z, a_pre[rr * 2 + 1].w);
        *(uint4*)&As[nxt][(arow + rr * 64) * 40 + acol] = pk;
      }
    }
    __syncthreads();
  }

  // epilogue: C/D layout col=lane&15, row=quad*4+reg (m89/m91-verified)
  const int b = m_blk >> 5;  // 32 m-tiles per batch row (T/128)
  float w2v[4], vv[4];
#pragma unroll
  for (int j = 0; j < 4; j++) {
    const int h = n_blk * 128 + wn * 64 + j * 16 + l16;
    w2v[j] = w2d[b * H_ + h];
    vv[j] = V[h];
  }
  float rs[4][4];
#pragma unroll
  for (int i = 0; i < 4; i++)
#pragma unroll
    for (int r = 0; r < 4; r++) {
      float s = 0.f;
#pragma unroll
      for (int j = 0; j < 4; j++) s += tanh_fast(acc[i][j][r] + w2v[j]) * vv[j];
      rs[i][r] = s;
    }
#pragma unroll
  for (int i = 0; i < 4; i++)
#pragma unroll
    for (int r = 0; r < 4; r++) {
      float s = rs[i][r];
      s += __shfl_xor(s, 1, 16);
      s += __shfl_xor(s, 2, 16);
      s += __shfl_xor(s, 4, 16);
      s += __shfl_xor(s, 8, 16);
      rs[i][r] = s;
    }
  if (l16 == 0) {
#pragma unroll
    for (int i = 0; i < 4; i++)
#pragma unroll
      for (int r = 0; r < 4; r++)
        atomicAdd(&scores[m_blk * 128 + wm * 64 + i * 16 + quad * 4 + r], rs[i][r]);
  }
}

// ---- softmax over T per batch row ----
__global__ __launch_bounds__(256) void softmax_rows(const float* __restrict__ scores,
                                                    float* __restrict__ out) {
  const int b = blockIdx.x;
  const int tid = threadIdx.x;
  const int wave = tid >> 6;
  __shared__ float red[4];
  float v[16];
  float mx = -1e30f;
#pragma unroll
  for (int i = 0; i < 16; i++) {
    v[i] = scores[b * T_ + i * 256 + tid];
    mx = fmaxf(mx, v[i]);
  }
#pragma unroll
  for (int o = 32; o > 0; o >>= 1) mx = fmaxf(mx, __shfl_xor(mx, o, 64));
  if ((tid & 63) == 0) red[wave] = mx;
  __syncthreads();
  mx = fmaxf(fmaxf(red[0], red[1]), fmaxf(red[2], red[3]));
  __syncthreads();
  float sum = 0.f;
#pragma unroll
  for (int i = 0; i < 16; i++) {
    v[i] = __expf(v[i] - mx);
    sum += v[i];
  }
#pragma unroll
  for (int o = 32; o > 0; o >>= 1) sum += __shfl_xor(sum, o, 64);
  if ((tid & 63) == 0) red[wave] = sum;
  __syncthreads();
  sum = (red[0] + red[1]) + (red[2] + red[3]);
  const float inv = 1.0f / sum;
#pragma unroll
  for (int i = 0; i < 16; i++) out[b * T_ + i * 256 + tid] = v[i] * inv;
}

extern "C" void kernel_launch(void* const* d_in, const int* in_sizes, int n_in,
                              void* d_out, int out_size, void* d_ws, size_t ws_size,
                              hipStream_t stream) {
  const float* enc = (const float*)d_in[0];  // [B,T,F]
  const float* dec = (const float*)d_in[1];  // [B,F]
  const float* W1 = (const float*)d_in[2];   // [F,H]
  const float* W2 = (const float*)d_in[3];   // [F,H]
  const float* V = (const float*)d_in[4];    // [H,1]
  float* out = (float*)d_out;                // [B,T]

  char* ws = (char*)d_ws;
  float* scores = (float*)ws;                            // 512 KB
  unsigned short* W1T = (unsigned short*)(ws + 524288);  // 512 KB
  float* w2d = (float*)(ws + 1048576);                   // 64 KB

  (void)in_sizes; (void)n_in; (void)out_size; (void)ws_size;

  hipMemsetAsync(scores, 0, B_ * T_ * sizeof(float), stream);
  prep_w1t<<<dim3(16, 16), dim3(32, 32), 0, stream>>>(W1, W1T);
  prep_w2d<<<dim3(32, 4), dim3(128), 0, stream>>>(dec, W2, w2d);
  fused_score<<<dim3(4096), dim3(256), 0, stream>>>(enc, W1T, w2d, V, scores);
  softmax_rows<<<dim3(32), dim3(256), 0, stream>>>(scores, out);
}